// Round 2
// baseline (650.941 us; speedup 1.0000x reference)
//
#include <hip/hip_runtime.h>
#include <hip/hip_bf16.h>
#include <stdint.h>

#define NE 128
#define NI 1856
#define NKK 6
#define NH 512
#define NT 4096
#define CAP 320
#define NPAIR (NT*NKK)
#define LD2I (2*NI)

typedef unsigned short u16;
typedef __attribute__((ext_vector_type(4))) float f32x4;
typedef __attribute__((ext_vector_type(8))) short bf16x8;
typedef __attribute__((ext_vector_type(4))) short s16x4;
typedef const void __attribute__((address_space(1)))* gas1p;
typedef void __attribute__((address_space(3)))* gas3p;

__device__ __forceinline__ short f2bf(float f) {
  union { __hip_bfloat16 h; short s; } c; c.h = __float2bfloat16(f); return c.s;
}
__device__ __forceinline__ float bf2f(short s) {
  union { float f; unsigned u; } v; v.u = ((unsigned)(u16)s) << 16; return v.f;
}

// ---------------- routing ----------------
__global__ void k_route(const int* __restrict__ topk, int* __restrict__ counts,
                        int* __restrict__ slot_of_pair, int* __restrict__ pair_of_slot) {
  int n = blockIdx.x * 256 + threadIdx.x;
  if (n >= NPAIR) return;
  int e = topk[n];
  int p = atomicAdd(&counts[e], 1);
  int s = (p < CAP) ? e * CAP + p : -1;
  slot_of_pair[n] = s;
  if (s >= 0) pair_of_slot[s] = n;
}

// ---------------- gather: hidden(f32) -> Xbuf(bf16) ----------------
__global__ void k_gather(const float* __restrict__ hid, const int* __restrict__ counts,
                         const int* __restrict__ pair_of_slot, u16* __restrict__ xbuf) {
  int t = threadIdx.x;
  int row = blockIdx.x * 2 + (t >> 7);
  int c = t & 127;
  int e = row / CAP, p = row % CAP;
  if (p >= counts[e]) return;
  int n = pair_of_slot[row];
  int tok = n / NKK;
  f32x4 v = *(const f32x4*)(hid + (size_t)tok * NH + c * 4);
  s16x4 o;
  o[0] = f2bf(v[0]); o[1] = f2bf(v[1]); o[2] = f2bf(v[2]); o[3] = f2bf(v[3]);
  *(s16x4*)(xbuf + (size_t)row * NH + c * 4) = o;
}

// ---------------- GEMM1: X[rows,H] @ Wgu[H,2I] -> silu(g)*u -> inter(bf16) ----------------
__global__ __launch_bounds__(256, 2) void k_gemm1(
    const u16* __restrict__ xbuf, const float* __restrict__ wgu,
    const int* __restrict__ counts, u16* __restrict__ inter, int e0)
{
  __shared__ __align__(16) char lds[32768];
  int bid = blockIdx.x;
  int mt = bid % 3;
  int nt = (bid / 3) % 29;
  int el = bid / 87;
  int e = e0 + el;
  int cnt = counts[e];
  int row0 = mt * 128;
  if (row0 >= cnt) return;
  int n0 = nt * 64;
  int t = threadIdx.x, w = t >> 6, l = t & 63;
  int wm = w >> 1, wc = w & 1;
  const char* abase = (const char*)(xbuf + (size_t)e * CAP * NH);

  auto stage = [&](int buf, int kt) {
    char* dstb = lds + buf * 16384;
    #pragma unroll
    for (int i = 0; i < 4; ++i) {
      int seg = i * 4 + w;
      int o = seg * 1024 + l * 16;
      int r = o >> 7;
      int inner = o & 127;
      int si = inner ^ ((r & 7) << 4);
      int grow = row0 + r; grow = grow < CAP ? grow : CAP - 1;
      const char* g = abase + (size_t)grow * (NH * 2) + kt * 128 + si;
      __builtin_amdgcn_global_load_lds((gas1p)g, (gas3p)(dstb + seg * 1024), 16, 0, 0);
    }
  };

  f32x4 acc[4][4];
  #pragma unroll
  for (int m = 0; m < 4; ++m)
    #pragma unroll
    for (int b = 0; b < 4; ++b) acc[m][b] = (f32x4){0.f, 0.f, 0.f, 0.f};

  stage(0, 0);
  const float* wbase = wgu + (size_t)e * NH * LD2I + n0 + wc * 32 + (l & 15);

  for (int kt = 0; kt < 8; ++kt) {
    __syncthreads();
    if (kt + 1 < 8) stage((kt + 1) & 1, kt + 1);
    const char* abuf = lds + (kt & 1) * 16384;
    #pragma unroll
    for (int ks = 0; ks < 2; ++ks) {
      int krow = kt * 64 + ks * 32 + ((l >> 4) << 3);
      const float* bp = wbase + (size_t)krow * LD2I;
      float bv[4][8];
      #pragma unroll
      for (int nf = 0; nf < 2; ++nf)
        #pragma unroll
        for (int j = 0; j < 8; ++j) {
          bv[nf][j]     = bp[(size_t)j * LD2I + nf * 16];
          bv[2 + nf][j] = bp[(size_t)j * LD2I + nf * 16 + NI];
        }
      bf16x8 bfrag[4];
      #pragma unroll
      for (int b = 0; b < 4; ++b)
        #pragma unroll
        for (int j = 0; j < 8; ++j) bfrag[b][j] = f2bf(bv[b][j]);
      bf16x8 afrag[4];
      #pragma unroll
      for (int mf = 0; mf < 4; ++mf) {
        int r = wm * 64 + mf * 16 + (l & 15);
        int inner = (ks * 64 + ((l >> 4) << 4)) ^ ((r & 7) << 4);
        afrag[mf] = *(const bf16x8*)(abuf + r * 128 + inner);
      }
      #pragma unroll
      for (int mf = 0; mf < 4; ++mf)
        #pragma unroll
        for (int b = 0; b < 4; ++b)
          acc[mf][b] = __builtin_amdgcn_mfma_f32_16x16x32_bf16(afrag[mf], bfrag[b], acc[mf][b], 0, 0, 0);
    }
  }

  // barrier: last K-step's cross-wave ds_reads must finish before we overwrite LDS
  __syncthreads();

  // epilogue: silu(gate)*up -> bf16, LDS repack -> 128B-per-row stores
  int vmax = cnt < CAP ? cnt : CAP;
  int rmax = vmax - row0; if (rmax > 128) rmax = 128;
  char* rb = lds;
  #pragma unroll
  for (int mf = 0; mf < 4; ++mf)
    #pragma unroll
    for (int nf = 0; nf < 2; ++nf) {
      f32x4 g = acc[mf][nf], u = acc[mf][2 + nf];
      #pragma unroll
      for (int r = 0; r < 4; ++r) {
        float gv = g[r];
        float sv = gv / (1.f + __expf(-gv));
        float val = sv * u[r];
        int rl = wm * 64 + mf * 16 + ((l >> 4) << 2) + r;
        int cl = wc * 32 + nf * 16 + (l & 15);
        *(short*)(rb + rl * 128 + ((cl * 2) ^ ((rl & 7) << 4))) = f2bf(val);
      }
    }
  __syncthreads();
  u16* obase = inter + (size_t)(el * CAP + row0) * NI + n0;
  #pragma unroll
  for (int i = 0; i < 4; ++i) {
    int task = i * 256 + t;
    int r = task >> 3, part = task & 7;
    if (r < rmax) {
      bf16x8 v = *(const bf16x8*)(rb + r * 128 + ((part * 16) ^ ((r & 7) << 4)));
      *(bf16x8*)(obase + (size_t)r * NI + part * 8) = v;
    }
  }
}

// ---------------- GEMM2: inter[rows,I] @ Wdn[I,H] -> Y(bf16) ----------------
__global__ __launch_bounds__(256, 2) void k_gemm2(
    const u16* __restrict__ inter, const float* __restrict__ wdn,
    const int* __restrict__ counts, u16* __restrict__ Y, int e0)
{
  __shared__ __align__(16) char lds[32768];
  int bid = blockIdx.x;
  int mt = bid % 3;
  int nt = (bid / 3) & 7;
  int el = bid / 24;
  int e = e0 + el;
  int cnt = counts[e];
  int row0 = mt * 128;
  if (row0 >= cnt) return;
  int n0 = nt * 64;
  int t = threadIdx.x, w = t >> 6, l = t & 63;
  int wm = w >> 1, wc = w & 1;
  const char* abase = (const char*)(inter + (size_t)el * CAP * NI);

  auto stage = [&](int buf, int kt) {
    char* dstb = lds + buf * 16384;
    #pragma unroll
    for (int i = 0; i < 4; ++i) {
      int seg = i * 4 + w;
      int o = seg * 1024 + l * 16;
      int r = o >> 7;
      int inner = o & 127;
      int si = inner ^ ((r & 7) << 4);
      int grow = row0 + r; grow = grow < CAP ? grow : CAP - 1;
      const char* g = abase + (size_t)grow * (NI * 2) + kt * 128 + si;
      __builtin_amdgcn_global_load_lds((gas1p)g, (gas3p)(dstb + seg * 1024), 16, 0, 0);
    }
  };

  f32x4 acc[4][2];
  #pragma unroll
  for (int m = 0; m < 4; ++m) { acc[m][0] = (f32x4){0.f,0.f,0.f,0.f}; acc[m][1] = (f32x4){0.f,0.f,0.f,0.f}; }

  stage(0, 0);
  const float* wbase = wdn + (size_t)e * NI * NH + n0 + wc * 32 + (l & 15);

  for (int kt = 0; kt < 29; ++kt) {
    __syncthreads();
    if (kt + 1 < 29) stage((kt + 1) & 1, kt + 1);
    const char* abuf = lds + (kt & 1) * 16384;
    #pragma unroll
    for (int ks = 0; ks < 2; ++ks) {
      int krow = kt * 64 + ks * 32 + ((l >> 4) << 3);
      const float* bp = wbase + (size_t)krow * NH;
      float bv[2][8];
      #pragma unroll
      for (int nf = 0; nf < 2; ++nf)
        #pragma unroll
        for (int j = 0; j < 8; ++j) bv[nf][j] = bp[(size_t)j * NH + nf * 16];
      bf16x8 bfrag[2];
      #pragma unroll
      for (int b = 0; b < 2; ++b)
        #pragma unroll
        for (int j = 0; j < 8; ++j) bfrag[b][j] = f2bf(bv[b][j]);
      bf16x8 afrag[4];
      #pragma unroll
      for (int mf = 0; mf < 4; ++mf) {
        int r = wm * 64 + mf * 16 + (l & 15);
        int inner = (ks * 64 + ((l >> 4) << 4)) ^ ((r & 7) << 4);
        afrag[mf] = *(const bf16x8*)(abuf + r * 128 + inner);
      }
      #pragma unroll
      for (int mf = 0; mf < 4; ++mf)
        #pragma unroll
        for (int b = 0; b < 2; ++b)
          acc[mf][b] = __builtin_amdgcn_mfma_f32_16x16x32_bf16(afrag[mf], bfrag[b], acc[mf][b], 0, 0, 0);
    }
  }

  // barrier: kt=28 (even) read buf0; epilogue writes buf0 -> must sync first
  __syncthreads();

  int vmax = cnt < CAP ? cnt : CAP;
  int rmax = vmax - row0; if (rmax > 128) rmax = 128;
  char* rb = lds;
  #pragma unroll
  for (int mf = 0; mf < 4; ++mf)
    #pragma unroll
    for (int nf = 0; nf < 2; ++nf) {
      f32x4 a = acc[mf][nf];
      #pragma unroll
      for (int r = 0; r < 4; ++r) {
        int rl = wm * 64 + mf * 16 + ((l >> 4) << 2) + r;
        int cl = wc * 32 + nf * 16 + (l & 15);
        *(short*)(rb + rl * 128 + ((cl * 2) ^ ((rl & 7) << 4))) = f2bf(a[r]);
      }
    }
  __syncthreads();
  u16* obase = Y + (size_t)(e * CAP + row0) * NH + n0;
  #pragma unroll
  for (int i = 0; i < 4; ++i) {
    int task = i * 256 + t;
    int r = task >> 3, part = task & 7;
    if (r < rmax) {
      bf16x8 v = *(const bf16x8*)(rb + r * 128 + ((part * 16) ^ ((r & 7) << 4)));
      *(bf16x8*)(obase + (size_t)r * NH + part * 8) = v;
    }
  }
}

// ---------------- combine: out[t] = sum_k w * Y[slot] (both copies) ----------------
__global__ void k_combine(const int* __restrict__ slot_of_pair, const float* __restrict__ wts,
                          const u16* __restrict__ Y, float* __restrict__ out)
{
  int t = threadIdx.x;
  int tok = blockIdx.x * 2 + (t >> 7);
  int c = t & 127;
  f32x4 a = (f32x4){0.f, 0.f, 0.f, 0.f};
  #pragma unroll
  for (int k = 0; k < NKK; ++k) {
    int n = tok * NKK + k;
    int s = slot_of_pair[n];
    if (s >= 0) {
      float wv = wts[n];
      s16x4 y = *(const s16x4*)(Y + (size_t)s * NH + c * 4);
      a[0] += wv * bf2f(y[0]);
      a[1] += wv * bf2f(y[1]);
      a[2] += wv * bf2f(y[2]);
      a[3] += wv * bf2f(y[3]);
    }
  }
  *(f32x4*)(out + (size_t)tok * NH + c * 4) = a;
  *(f32x4*)(out + (size_t)(NT + tok) * NH + c * 4) = a;
}

extern "C" void kernel_launch(void* const* d_in, const int* in_sizes, int n_in,
                              void* d_out, int out_size, void* d_ws, size_t ws_size,
                              hipStream_t stream) {
  const float* hid  = (const float*)d_in[0];
  const int*   topk = (const int*)d_in[1];
  const float* wts  = (const float*)d_in[2];
  const float* wgu  = (const float*)d_in[3];
  const float* wdn  = (const float*)d_in[4];

  char* ws = (char*)d_ws;
  size_t off = 0;
  auto alloc = [&](size_t sz) { char* p = ws + off; off = (off + sz + 255) & ~(size_t)255; return p; };
  int* counts        = (int*)alloc(NE * 4);
  int* slot_of_pair  = (int*)alloc((size_t)NPAIR * 4);
  int* pair_of_slot  = (int*)alloc((size_t)NE * CAP * 4);
  u16* xbuf          = (u16*)alloc((size_t)NE * CAP * NH * 2);
  u16* Y             = (u16*)alloc((size_t)NE * CAP * NH * 2);
  size_t remain = ws_size > off ? ws_size - off : 0;
  size_t per_e = (size_t)CAP * NI * 2;
  int chunkE = (int)(remain / per_e);
  if (chunkE > NE) chunkE = NE;
  if (chunkE < 1) chunkE = 1;
  u16* inter = (u16*)(ws + off);

  hipMemsetAsync(counts, 0, NE * 4, stream);
  k_route<<<NPAIR / 256, 256, 0, stream>>>(topk, counts, slot_of_pair, pair_of_slot);
  k_gather<<<NE * CAP / 2, 256, 0, stream>>>(hid, counts, pair_of_slot, xbuf);
  for (int e0 = 0; e0 < NE; e0 += chunkE) {
    int ce = NE - e0 < chunkE ? NE - e0 : chunkE;
    k_gemm1<<<ce * 29 * 3, 256, 0, stream>>>(xbuf, wgu, counts, inter, e0);
    k_gemm2<<<ce * 8 * 3, 256, 0, stream>>>(inter, wdn, counts, Y, e0);
  }
  k_combine<<<NT / 2, 256, 0, stream>>>(slot_of_pair, wts, Y, (float*)d_out);
}